// Round 5
// baseline (235.097 us; speedup 1.0000x reference)
//
#include <hip/hip_runtime.h>
#include <cstdint>
#include <cmath>

#define DENSITY   0.05f
#define TOP_IG    7
#define NT        256
#define FEAT      4096
#define FEAT4     1024
#define NREP      4            // pass-1 replicas per wave
#define RST       260          // replica stride in words: bank stagger 4, 16B-aligned
#define H1W       (NREP*RST)   // 1040 words
#define WREG      (H1W + 512)  // per-wave LDS words: hist1 + hist2[2][256] = 1552

typedef float vfloat4 __attribute__((ext_vector_type(4)));   // native vector for nt-store

// monotonic float -> uint order key (ascending float == ascending key)
__device__ __forceinline__ unsigned fkey(float f) {
    unsigned u = __float_as_uint(f);
    return (u & 0x80000000u) ? ~u : (u | 0x80000000u);
}

// ---------------- kernel 1: chunked column partial sums (whole-row streaming) ----------------
__global__ __launch_bounds__(NT)
void k_colsum_partial(const float4* __restrict__ x4, float4* __restrict__ part4,
                      int B, int F4v, int rowsPerChunk) {
    const int t = threadIdx.x;
    int r0 = blockIdx.x * rowsPerChunk;
    int r1 = r0 + rowsPerChunk; if (r1 > B) r1 = B;
    float4 a0 = make_float4(0.f,0.f,0.f,0.f), a1 = a0, a2 = a0, a3 = a0;
    for (int r = r0; r < r1; ++r) {
        const float4* __restrict__ row = x4 + (size_t)r * F4v;
        float4 v0 = row[t], v1 = row[t + 256], v2 = row[t + 512], v3 = row[t + 768];
        a0.x += v0.x; a0.y += v0.y; a0.z += v0.z; a0.w += v0.w;
        a1.x += v1.x; a1.y += v1.y; a1.z += v1.z; a1.w += v1.w;
        a2.x += v2.x; a2.y += v2.y; a2.z += v2.z; a2.w += v2.w;
        a3.x += v3.x; a3.y += v3.y; a3.z += v3.z; a3.w += v3.w;
    }
    float4* p = part4 + (size_t)blockIdx.x * F4v;
    p[t] = a0; p[t + 256] = a1; p[t + 512] = a2; p[t + 768] = a3;
}

// ------------- kernel 2: reduce partials -> mean; compute factor -------------
__global__ __launch_bounds__(NT)
void k_finalize_stats(const float4* __restrict__ part4, const float4* __restrict__ aa4,
                      float4* __restrict__ mean4, float4* __restrict__ factor4,
                      int B, int F4v, int nChunks) {
    __shared__ float4 red[4][64];
    int lane = threadIdx.x & 63;
    int q    = threadIdx.x >> 6;
    int cg   = blockIdx.x * 64 + lane;
    float4 s = make_float4(0.f, 0.f, 0.f, 0.f);
    if (cg < F4v) {
        for (int ch = q; ch < nChunks; ch += 4) {
            float4 v = part4[(size_t)ch * F4v + cg];
            s.x += v.x; s.y += v.y; s.z += v.z; s.w += v.w;
        }
    }
    red[q][lane] = s;
    __syncthreads();
    if (q == 0 && cg < F4v) {
        float4 a0 = red[0][lane], a1 = red[1][lane], a2 = red[2][lane], a3 = red[3][lane];
        float invB = 1.0f / (float)B;
        mean4[cg] = make_float4((a0.x + a1.x + a2.x + a3.x) * invB,
                                (a0.y + a1.y + a2.y + a3.y) * invB,
                                (a0.z + a1.z + a2.z + a3.z) * invB,
                                (a0.w + a1.w + a2.w + a3.w) * invB);
        float4 a = aa4[cg];
        factor4[cg] = make_float4((float)exp((double)(DENSITY - a.x)),
                                  (float)exp((double)(DENSITY - a.y)),
                                  (float)exp((double)(DENSITY - a.z)),
                                  (float)exp((double)(DENSITY - a.w)));
    }
}

// one radix step: counts c0..c3 for this lane's 4 bins -> update (pref, rr)
__device__ __forceinline__ void radix_step(unsigned c0, unsigned c1, unsigned c2, unsigned c3,
                                           int lane, unsigned& pref, unsigned& rr) {
    unsigned L = c0 + c1 + c2 + c3;
    unsigned P = L;
    #pragma unroll
    for (int off = 1; off < 64; off <<= 1) {
        unsigned n = __shfl_up(P, off, 64);
        if (lane >= off) P += n;
    }
    unsigned TOT = __shfl(P, 63, 64);
    unsigned SS0 = TOT - P + L;               // suffix sums: #keys with digit >= bin
    unsigned SS1 = SS0 - c0, SS2 = SS1 - c1, SS3 = SS2 - c2, SS4 = SS3 - c3;
    unsigned pack = 0; bool m = false;
    unsigned b0 = (unsigned)(lane << 2);
    if      (SS0 >= rr && SS1 < rr) { pack = ((b0+0u) << 16) | (rr - SS1); m = true; }
    else if (SS1 >= rr && SS2 < rr) { pack = ((b0+1u) << 16) | (rr - SS2); m = true; }
    else if (SS2 >= rr && SS3 < rr) { pack = ((b0+2u) << 16) | (rr - SS3); m = true; }
    else if (SS3 >= rr && SS4 < rr) { pack = ((b0+3u) << 16) | (rr - SS4); m = true; }
    unsigned long long mk = __ballot(m);
    int src = __ffsll((unsigned long long)mk) - 1;
    pack = __shfl(pack, src, 64);
    pref = (pref << 8) | (pack >> 16);
    rr   = pack & 0xffffu;
}

// ------------- kernel 3: ONE ROW PER WAVE, zero block barriers -------------
// 64 keys/lane in VGPRs; wave-private LDS histograms (in-order DS per wave
// makes atomic->read->zero->atomic sequences correct without __syncthreads).
__global__ __launch_bounds__(NT, 4)
void k_select_apply(const float4* __restrict__ x4, const float4* __restrict__ factor4,
                    const float4* __restrict__ mean4, float4* __restrict__ out4,
                    int rankHi, int rankLo, int B) {
    __shared__ __align__(16) unsigned lds[4][WREG];

    const int t    = threadIdx.x;
    const int wid  = t >> 6;
    const int lane = t & 63;
    const int row  = blockIdx.x * 4 + wid;
    if (row >= B) return;
    const size_t rowBase = (size_t)row * FEAT4;

    unsigned* __restrict__ W  = &lds[wid][0];   // this wave's region
    unsigned* __restrict__ H2 = W + H1W;        // [2][256]

    // ---- zero this wave's LDS region (no barrier needed: same wave uses it) ----
    for (int i = lane; i < WREG; i += 64) W[i] = 0u;

    // ---- load row, build order keys in registers (64/lane) ----
    unsigned kk[64];
    #pragma unroll
    for (int j = 0; j < 16; ++j) {
        int v = lane + 64 * j;
        float4 X  = x4[rowBase + v];
        float4 Fa = factor4[v];
        kk[4*j+0] = fkey(X.x * Fa.x);
        kk[4*j+1] = fkey(X.y * Fa.y);
        kk[4*j+2] = fkey(X.z * Fa.z);
        kk[4*j+3] = fkey(X.w * Fa.w);
    }

    // ---- pass 1 (bits 31..24): bank-staggered replicated histogram ----
    {
        unsigned* h1 = W + (unsigned)(lane >> 4) * RST;
        #pragma unroll
        for (int j = 0; j < 64; ++j)
            atomicAdd(&h1[kk[j] >> 24], 1u);
    }

    unsigned pref0 = 0u, rr0 = (unsigned)rankHi;
    unsigned pref1 = 0u, rr1 = (unsigned)rankLo;

    {   // merge replicas straight into registers (contiguous b128 reads)
        uint4 c = make_uint4(0u, 0u, 0u, 0u);
        #pragma unroll
        for (int r = 0; r < NREP; ++r) {
            uint4 h = *reinterpret_cast<const uint4*>(&W[r * RST + (lane << 2)]);
            c.x += h.x; c.y += h.y; c.z += h.z; c.w += h.w;
        }
        radix_step(c.x, c.y, c.z, c.w, lane, pref0, rr0);
        radix_step(c.x, c.y, c.z, c.w, lane, pref1, rr1);
    }

    // ---- passes 2..4: prefix-filtered, dual-target, single buffer ----
    #pragma unroll
    for (int pass = 0; pass < 3; ++pass) {
        const int shift = 16 - 8 * pass;
        #pragma unroll
        for (int j = 0; j < 64; ++j) {
            unsigned k  = kk[j];
            unsigned hi = k >> (shift + 8);
            unsigned d  = (k >> shift) & 255u;
            if (hi == pref0) atomicAdd(&H2[d], 1u);
            if (hi == pref1) atomicAdd(&H2[256 + d], 1u);
        }
        uint4 g0 = *reinterpret_cast<const uint4*>(&H2[lane << 2]);
        uint4 g1 = *reinterpret_cast<const uint4*>(&H2[256 + (lane << 2)]);
        if (pass < 2) {   // zero for next pass; DS is in-order per wave
            *reinterpret_cast<uint4*>(&H2[lane << 2])         = make_uint4(0u,0u,0u,0u);
            *reinterpret_cast<uint4*>(&H2[256 + (lane << 2)]) = make_uint4(0u,0u,0u,0u);
        }
        radix_step(g0.x, g0.y, g0.z, g0.w, lane, pref0, rr0);
        radix_step(g1.x, g1.y, g1.z, g1.w, lane, pref1, rr1);
    }

    // ---- apply masks: pref0/pref1 are the exact 32-bit keys of ranks 7/211 ----
    const unsigned keyHi = pref0;   // fkey(top_ig)
    const unsigned keyLo = pref1;   // fkey(kth)

    #pragma unroll
    for (int j = 0; j < 16; ++j) {
        int v = lane + 64 * j;
        float4 X = x4[rowBase + v];      // re-read: L2/L3-resident
        float4 M = mean4[v];
        unsigned k0 = kk[4*j+0], k1 = kk[4*j+1], k2 = kk[4*j+2], k3 = kk[4*j+3];
        vfloat4 o;
        o.x = (k0 <= keyHi) ? ((k0 >= keyLo) ? X.x - M.x : -M.x) : 0.0f;
        o.y = (k1 <= keyHi) ? ((k1 >= keyLo) ? X.y - M.y : -M.y) : 0.0f;
        o.z = (k2 <= keyHi) ? ((k2 >= keyLo) ? X.z - M.z : -M.z) : 0.0f;
        o.w = (k3 <= keyHi) ? ((k3 >= keyLo) ? X.w - M.w : -M.w) : 0.0f;
        __builtin_nontemporal_store(o, reinterpret_cast<vfloat4*>(&out4[rowBase + v]));
    }
}

extern "C" void kernel_launch(void* const* d_in, const int* in_sizes, int n_in,
                              void* d_out, int out_size, void* d_ws, size_t ws_size,
                              hipStream_t stream) {
    const float* x  = (const float*)d_in[0];
    const float* aa = (const float*)d_in[1];
    float* out = (float*)d_out;

    const int F   = in_sizes[1];          // 4096
    const int B   = in_sizes[0] / F;      // 8192
    const int F4v = F / 4;
    const int rankLo = (int)((double)F * 0.05) + TOP_IG;   // 211
    const int rankHi = TOP_IG;                              // 7

    int nChunks = 1024;
    while (nChunks > 1 &&
           ((size_t)nChunks + 2) * (size_t)F * sizeof(float) > ws_size)
        nChunks >>= 1;
    if (nChunks > B) nChunks = B;

    float* part   = (float*)d_ws;
    float* mean   = part + (size_t)nChunks * F;
    float* factor = mean + F;
    int rpc = (B + nChunks - 1) / nChunks;

    k_colsum_partial<<<dim3(nChunks), NT, 0, stream>>>(
        (const float4*)x, (float4*)part, B, F4v, rpc);

    k_finalize_stats<<<dim3((F4v + 63) / 64), NT, 0, stream>>>(
        (const float4*)part, (const float4*)aa, (float4*)mean, (float4*)factor, B, F4v, nChunks);

    k_select_apply<<<dim3((B + 3) / 4), NT, 0, stream>>>(
        (const float4*)x, (const float4*)factor, (const float4*)mean, (float4*)out,
        rankHi, rankLo, B);
}

// Round 6
// 158.324 us; speedup vs baseline: 1.4849x; 1.4849x over previous
//
#include <hip/hip_runtime.h>
#include <cstdint>
#include <cmath>

#define DENSITY   0.05f
#define TOP_IG    7
#define NT        256
#define FEAT      4096
#define FEAT4     1024
#define NBIN1     2048     // 11-bit pass-1 digit
#define CAP1      1024     // candidate cap, kth target (typ ~220)
#define CAP0      512      // candidate cap, top_ig target (typ ~10)
#define CAPF      64       // finalist cap (typ ~2)

typedef float vfloat4 __attribute__((ext_vector_type(4)));

// monotonic float -> uint order key (ascending float == ascending key)
__device__ __forceinline__ unsigned fkey(float f) {
    unsigned u = __float_as_uint(f);
    return (u & 0x80000000u) ? ~u : (u | 0x80000000u);
}

// ---------------- kernel 1: chunked column partial sums (whole-row streaming) ----------------
__global__ __launch_bounds__(NT)
void k_colsum_partial(const float4* __restrict__ x4, float4* __restrict__ part4,
                      int B, int F4v, int rowsPerChunk) {
    const int t = threadIdx.x;
    int r0 = blockIdx.x * rowsPerChunk;
    int r1 = r0 + rowsPerChunk; if (r1 > B) r1 = B;
    float4 a0 = make_float4(0.f,0.f,0.f,0.f), a1 = a0, a2 = a0, a3 = a0;
    for (int r = r0; r < r1; ++r) {
        const float4* __restrict__ row = x4 + (size_t)r * F4v;
        float4 v0 = row[t], v1 = row[t + 256], v2 = row[t + 512], v3 = row[t + 768];
        a0.x += v0.x; a0.y += v0.y; a0.z += v0.z; a0.w += v0.w;
        a1.x += v1.x; a1.y += v1.y; a1.z += v1.z; a1.w += v1.w;
        a2.x += v2.x; a2.y += v2.y; a2.z += v2.z; a2.w += v2.w;
        a3.x += v3.x; a3.y += v3.y; a3.z += v3.z; a3.w += v3.w;
    }
    float4* p = part4 + (size_t)blockIdx.x * F4v;
    p[t] = a0; p[t + 256] = a1; p[t + 512] = a2; p[t + 768] = a3;
}

// ------------- kernel 2: reduce partials -> mean; compute factor -------------
__global__ __launch_bounds__(NT)
void k_finalize_stats(const float4* __restrict__ part4, const float4* __restrict__ aa4,
                      float4* __restrict__ mean4, float4* __restrict__ factor4,
                      int B, int F4v, int nChunks) {
    __shared__ float4 red[4][64];
    int lane = threadIdx.x & 63;
    int q    = threadIdx.x >> 6;
    int cg   = blockIdx.x * 64 + lane;
    float4 s = make_float4(0.f, 0.f, 0.f, 0.f);
    if (cg < F4v) {
        for (int ch = q; ch < nChunks; ch += 4) {
            float4 v = part4[(size_t)ch * F4v + cg];
            s.x += v.x; s.y += v.y; s.z += v.z; s.w += v.w;
        }
    }
    red[q][lane] = s;
    __syncthreads();
    if (q == 0 && cg < F4v) {
        float4 a0 = red[0][lane], a1 = red[1][lane], a2 = red[2][lane], a3 = red[3][lane];
        float invB = 1.0f / (float)B;
        mean4[cg] = make_float4((a0.x + a1.x + a2.x + a3.x) * invB,
                                (a0.y + a1.y + a2.y + a3.y) * invB,
                                (a0.z + a1.z + a2.z + a3.z) * invB,
                                (a0.w + a1.w + a2.w + a3.w) * invB);
        float4 a = aa4[cg];
        factor4[cg] = make_float4((float)exp((double)(DENSITY - a.x)),
                                  (float)exp((double)(DENSITY - a.y)),
                                  (float)exp((double)(DENSITY - a.z)),
                                  (float)exp((double)(DENSITY - a.w)));
    }
}

// wave inclusive scan + total of per-lane value
__device__ __forceinline__ void wscan(unsigned T, int lane, unsigned& incl, unsigned& tot) {
    unsigned P = T;
    #pragma unroll
    for (int off = 1; off < 64; off <<= 1) {
        unsigned n = __shfl_up(P, off, 64);
        if (lane >= off) P += n;
    }
    incl = P;
    tot = __shfl(P, 63, 64);
}

// find rank rr_in in 2048-bin histogram (lane owns bins [lane*32, lane*32+32))
__device__ __forceinline__ void resolve2048(const unsigned* hist, int lane,
                                            unsigned T, unsigned above,
                                            unsigned rr_in, unsigned& bin, unsigned& rr) {
    bool hit = (above < rr_in) && (rr_in <= above + T);
    unsigned long long mk = __ballot(hit);
    int src = __ffsll(mk) - 1;
    unsigned aboveS = __shfl(above, src, 64);
    int j = lane & 31;
    unsigned cj = hist[(src << 5) + j];               // consecutive words: conflict-free
    unsigned P = cj;
    #pragma unroll
    for (int off = 1; off < 32; off <<= 1) {          // width-32 scan (both halves identical)
        unsigned n = __shfl_up(P, off, 32);
        if (j >= off) P += n;
    }
    unsigned T32 = __shfl(P, 31, 32);
    unsigned above_j = aboveS + T32 - P;              // keys strictly above bin src*32+j
    bool h2 = (above_j < rr_in) && (rr_in <= above_j + cj);
    unsigned long long mk2 = __ballot(h2);
    int src2 = __ffsll(mk2) - 1;
    bin = ((unsigned)src << 5) | (unsigned)(src2 & 31);
    rr  = rr_in - __shfl(above_j, src2, 64);
}

// find rank rr_in in 256-bin histogram (lane owns 4 bins via uint4)
__device__ __forceinline__ void select256(const unsigned* h, int lane,
                                          unsigned rr_in, unsigned& sub, unsigned& rr) {
    uint4 c = *reinterpret_cast<const uint4*>(&h[lane << 2]);
    unsigned T = c.x + c.y + c.z + c.w;
    unsigned incl, tot; wscan(T, lane, incl, tot);
    unsigned above = tot - incl;
    bool hit = (above < rr_in) && (rr_in <= above + T);
    unsigned long long mk = __ballot(hit);
    int src = __ffsll(mk) - 1;
    unsigned aS = __shfl(above, src, 64);
    unsigned c0 = __shfl(c.x, src, 64), c1 = __shfl(c.y, src, 64);
    unsigned c2 = __shfl(c.z, src, 64), c3 = __shfl(c.w, src, 64);
    unsigned a3 = aS, a2 = a3 + c3, a1 = a2 + c2, a0 = a1 + c1;
    unsigned b, a;
    if      (a3 < rr_in && rr_in <= a3 + c3) { b = 3u; a = a3; }
    else if (a2 < rr_in && rr_in <= a2 + c2) { b = 2u; a = a2; }
    else if (a1 < rr_in && rr_in <= a1 + c1) { b = 1u; a = a1; }
    else                                     { b = 0u; a = a0; }
    sub = ((unsigned)src << 2) | b;
    rr  = rr_in - a;
}

// ------------- kernel 3: block-per-row, candidate-compaction dual select -------------
__global__ __launch_bounds__(NT)
void k_select_apply(const float4* __restrict__ x4, const float4* __restrict__ factor4,
                    const float4* __restrict__ mean4, float4* __restrict__ out4,
                    int rankHi, int rankLo) {
    __shared__ __align__(16) unsigned hist1[NBIN1];
    __shared__ __align__(16) unsigned h8[2][256];
    __shared__ unsigned candK[CAP1];
    __shared__ unsigned candS[CAP0];
    __shared__ unsigned fin[2][CAPF];
    __shared__ unsigned cnts[4];     // [0]=cand kth, [1]=cand top, [2]=fin kth, [3]=fin top
    __shared__ unsigned res[2];      // [0]=keyHi(rank7), [1]=keyLo(rank211)

    const int t    = threadIdx.x;
    const int wid  = t >> 6;
    const int lane = t & 63;
    const size_t rowBase = (size_t)blockIdx.x * FEAT4;

    // ---- zero ----
    #pragma unroll
    for (int i = 0; i < NBIN1 / NT; ++i) hist1[t + NT * i] = 0u;
    h8[0][t] = 0u; h8[1][t] = 0u;
    if (t < 4) cnts[t] = 0u;
    __syncthreads();                                   // B1

    // ---- phase A: keygen (keys stay in VGPRs) + 11-bit histogram ----
    unsigned kk[16];
    #pragma unroll
    for (int jj = 0; jj < 4; ++jj) {
        int v = t + NT * jj;
        float4 X  = x4[rowBase + v];
        float4 Fa = factor4[v];
        unsigned k0 = fkey(X.x * Fa.x), k1 = fkey(X.y * Fa.y);
        unsigned k2 = fkey(X.z * Fa.z), k3 = fkey(X.w * Fa.w);
        kk[4*jj+0] = k0; kk[4*jj+1] = k1; kk[4*jj+2] = k2; kk[4*jj+3] = k3;
        atomicAdd(&hist1[k0 >> 21], 1u);
        atomicAdd(&hist1[k1 >> 21], 1u);
        atomicAdd(&hist1[k2 >> 21], 1u);
        atomicAdd(&hist1[k3 >> 21], 1u);
    }
    __syncthreads();                                   // B2

    // ---- phase B: one scan of 2048 bins resolves BOTH ranks (redundant per wave) ----
    unsigned bin0, rr0, bin1, rr1;
    {
        unsigned T = 0;
        #pragma unroll
        for (int j = 0; j < 32; ++j)                   // bank-rotated: conflict-free
            T += hist1[(lane << 5) + ((j + lane) & 31)];
        unsigned incl, tot; wscan(T, lane, incl, tot);
        unsigned above = tot - incl;
        resolve2048(hist1, lane, T, above, (unsigned)rankHi, bin0, rr0);
        resolve2048(hist1, lane, T, above, (unsigned)rankLo, bin1, rr1);
    }

    // ---- phase C: compact candidates + fused 8-bit sub-histograms ----
    #pragma unroll
    for (int j = 0; j < 16; ++j) {
        unsigned k = kk[j];
        unsigned d = k >> 21;
        if (d == bin1) {
            unsigned idx = atomicAdd(&cnts[0], 1u);
            if (idx < CAP1) { candK[idx] = k; atomicAdd(&h8[1][(k >> 13) & 255u], 1u); }
        }
        if (d == bin0) {
            unsigned idx = atomicAdd(&cnts[1], 1u);
            if (idx < CAP0) { candS[idx] = k; atomicAdd(&h8[0][(k >> 13) & 255u], 1u); }
        }
    }
    __syncthreads();                                   // B3

    // ---- phase D: resolve 8-bit sub-digit within each candidate pool ----
    unsigned sub0, rr0f, sub1, rr1f;
    select256(&h8[0][0], lane, rr0, sub0, rr0f);
    select256(&h8[1][0], lane, rr1, sub1, rr1f);

    // ---- phase E: gather finalists (19-bit prefix match) ----
    {
        unsigned pre1 = (bin1 << 8) | sub1;
        unsigned pre0 = (bin0 << 8) | sub0;
        unsigned K1c = cnts[0]; if (K1c > CAP1) K1c = CAP1;
        for (unsigned i = t; i < K1c; i += NT) {
            unsigned k = candK[i];
            if ((k >> 13) == pre1) { unsigned f = atomicAdd(&cnts[2], 1u); if (f < CAPF) fin[1][f] = k; }
        }
        unsigned K0c = cnts[1]; if (K0c > CAP0) K0c = CAP0;
        for (unsigned i = t; i < K0c; i += NT) {
            unsigned k = candS[i];
            if ((k >> 13) == pre0) { unsigned f = atomicAdd(&cnts[3], 1u); if (f < CAPF) fin[0][f] = k; }
        }
    }
    __syncthreads();                                   // B4

    // ---- phase F: exact rank by duplicate-aware counting (waves 0,1 in parallel) ----
    if (wid < 2) {
        unsigned K  = cnts[wid == 0 ? 3 : 2]; if (K > CAPF) K = CAPF;
        unsigned rr = (wid == 0) ? rr0f : rr1f;
        unsigned myk = fin[wid][lane < (int)K ? lane : 0];
        unsigned gt = 0, eq = 0;
        for (unsigned i = 0; i < K; ++i) {
            unsigned v = fin[wid][i];                  // broadcast read
            gt += (v > myk) ? 1u : 0u;
            eq += (v == myk) ? 1u : 0u;
        }
        bool hit = (lane < (int)K) && (gt < rr) && (rr <= gt + eq);
        unsigned long long mk = __ballot(hit);
        int src = __ffsll(mk) - 1;
        unsigned key = __shfl(myk, src, 64);
        if (lane == 0) res[wid] = key;
    }
    __syncthreads();                                   // B5

    // ---- phase G: apply masks (x re-read: L1/L2-hot) ----
    const unsigned keyHi = res[0];
    const unsigned keyLo = res[1];
    #pragma unroll
    for (int jj = 0; jj < 4; ++jj) {
        int v = t + NT * jj;
        float4 X = x4[rowBase + v];
        float4 M = mean4[v];
        unsigned k0 = kk[4*jj+0], k1 = kk[4*jj+1], k2 = kk[4*jj+2], k3 = kk[4*jj+3];
        vfloat4 o;
        o.x = (k0 <= keyHi) ? ((k0 >= keyLo) ? X.x - M.x : -M.x) : 0.0f;
        o.y = (k1 <= keyHi) ? ((k1 >= keyLo) ? X.y - M.y : -M.y) : 0.0f;
        o.z = (k2 <= keyHi) ? ((k2 >= keyLo) ? X.z - M.z : -M.z) : 0.0f;
        o.w = (k3 <= keyHi) ? ((k3 >= keyLo) ? X.w - M.w : -M.w) : 0.0f;
        __builtin_nontemporal_store(o, reinterpret_cast<vfloat4*>(&out4[rowBase + v]));
    }
}

extern "C" void kernel_launch(void* const* d_in, const int* in_sizes, int n_in,
                              void* d_out, int out_size, void* d_ws, size_t ws_size,
                              hipStream_t stream) {
    const float* x  = (const float*)d_in[0];
    const float* aa = (const float*)d_in[1];
    float* out = (float*)d_out;

    const int F   = in_sizes[1];          // 4096
    const int B   = in_sizes[0] / F;      // 8192
    const int F4v = F / 4;
    const int rankLo = (int)((double)F * 0.05) + TOP_IG;   // 211
    const int rankHi = TOP_IG;                              // 7

    int nChunks = 1024;
    while (nChunks > 1 &&
           ((size_t)nChunks + 2) * (size_t)F * sizeof(float) > ws_size)
        nChunks >>= 1;
    if (nChunks > B) nChunks = B;

    float* part   = (float*)d_ws;
    float* mean   = part + (size_t)nChunks * F;
    float* factor = mean + F;
    int rpc = (B + nChunks - 1) / nChunks;

    k_colsum_partial<<<dim3(nChunks), NT, 0, stream>>>(
        (const float4*)x, (float4*)part, B, F4v, rpc);

    k_finalize_stats<<<dim3((F4v + 63) / 64), NT, 0, stream>>>(
        (const float4*)part, (const float4*)aa, (float4*)mean, (float4*)factor, B, F4v, nChunks);

    k_select_apply<<<dim3(B), NT, 0, stream>>>(
        (const float4*)x, (const float4*)factor, (const float4*)mean, (float4*)out,
        rankHi, rankLo);
}

// Round 7
// 113.055 us; speedup vs baseline: 2.0795x; 1.4004x over previous
//
#include <hip/hip_runtime.h>
#include <cstdint>
#include <cmath>

#define DENSITY   0.05f
#define TOP_IG    7
#define NT        256
#define NT1       64
#define FEAT      4096
#define FEAT4     1024
#define NBIN1     2048     // 11-bit pass-1 digit
#define CAP1      1024     // candidate cap, kth target (typ ~220)
#define CAP0      512      // candidate cap, top_ig target (typ ~10)
#define CAPF      64       // finalist cap (typ ~2)

typedef float vfloat4 __attribute__((ext_vector_type(4)));

// monotonic float -> uint order key (ascending float == ascending key)
__device__ __forceinline__ unsigned fkey(float f) {
    unsigned u = __float_as_uint(f);
    return (u & 0x80000000u) ? ~u : (u | 0x80000000u);
}

// ---------------- kernel 1: chunked column partial sums (R3 geometry) ----------------
__global__ __launch_bounds__(NT1)
void k_colsum_partial(const float4* __restrict__ x4, float4* __restrict__ part4,
                      int B, int F4v, int rowsPerChunk) {
    int cg = blockIdx.x * NT1 + threadIdx.x;
    if (cg >= F4v) return;
    int r0 = blockIdx.y * rowsPerChunk;
    int r1 = r0 + rowsPerChunk; if (r1 > B) r1 = B;
    float4 s0 = make_float4(0.f,0.f,0.f,0.f), s1 = s0, s2 = s0, s3 = s0;
    int r = r0;
    for (; r + 4 <= r1; r += 4) {
        float4 a = x4[(size_t)(r+0) * F4v + cg];
        float4 b = x4[(size_t)(r+1) * F4v + cg];
        float4 c = x4[(size_t)(r+2) * F4v + cg];
        float4 d = x4[(size_t)(r+3) * F4v + cg];
        s0.x += a.x; s0.y += a.y; s0.z += a.z; s0.w += a.w;
        s1.x += b.x; s1.y += b.y; s1.z += b.z; s1.w += b.w;
        s2.x += c.x; s2.y += c.y; s2.z += c.z; s2.w += c.w;
        s3.x += d.x; s3.y += d.y; s3.z += d.z; s3.w += d.w;
    }
    for (; r < r1; ++r) {
        float4 a = x4[(size_t)r * F4v + cg];
        s0.x += a.x; s0.y += a.y; s0.z += a.z; s0.w += a.w;
    }
    float4 s = make_float4(s0.x+s1.x+s2.x+s3.x, s0.y+s1.y+s2.y+s3.y,
                           s0.z+s1.z+s2.z+s3.z, s0.w+s1.w+s2.w+s3.w);
    part4[(size_t)blockIdx.y * F4v + cg] = s;
}

// ------------- kernel 2: reduce partials -> mean; compute factor (R3) -------------
__global__ __launch_bounds__(NT)
void k_finalize_stats(const float4* __restrict__ part4, const float4* __restrict__ aa4,
                      float4* __restrict__ mean4, float4* __restrict__ factor4,
                      int B, int F4v, int nChunks) {
    __shared__ float4 red[4][64];
    int lane = threadIdx.x & 63;
    int q    = threadIdx.x >> 6;
    int cg   = blockIdx.x * 64 + lane;
    float4 s = make_float4(0.f, 0.f, 0.f, 0.f);
    if (cg < F4v) {
        for (int ch = q; ch < nChunks; ch += 4) {
            float4 v = part4[(size_t)ch * F4v + cg];
            s.x += v.x; s.y += v.y; s.z += v.z; s.w += v.w;
        }
    }
    red[q][lane] = s;
    __syncthreads();
    if (q == 0 && cg < F4v) {
        float4 a0 = red[0][lane], a1 = red[1][lane], a2 = red[2][lane], a3 = red[3][lane];
        float invB = 1.0f / (float)B;
        mean4[cg] = make_float4((a0.x + a1.x + a2.x + a3.x) * invB,
                                (a0.y + a1.y + a2.y + a3.y) * invB,
                                (a0.z + a1.z + a2.z + a3.z) * invB,
                                (a0.w + a1.w + a2.w + a3.w) * invB);
        float4 a = aa4[cg];
        factor4[cg] = make_float4((float)exp((double)(DENSITY - a.x)),
                                  (float)exp((double)(DENSITY - a.y)),
                                  (float)exp((double)(DENSITY - a.z)),
                                  (float)exp((double)(DENSITY - a.w)));
    }
}

// wave inclusive scan + total of per-lane value
__device__ __forceinline__ void wscan(unsigned T, int lane, unsigned& incl, unsigned& tot) {
    unsigned P = T;
    #pragma unroll
    for (int off = 1; off < 64; off <<= 1) {
        unsigned n = __shfl_up(P, off, 64);
        if (lane >= off) P += n;
    }
    incl = P;
    tot = __shfl(P, 63, 64);
}

// find rank rr_in in 2048-bin histogram (lane owns bins [lane*32, lane*32+32))
__device__ __forceinline__ void resolve2048(const unsigned* hist, int lane,
                                            unsigned T, unsigned above,
                                            unsigned rr_in, unsigned& bin, unsigned& rr) {
    bool hit = (above < rr_in) && (rr_in <= above + T);
    unsigned long long mk = __ballot(hit);
    int src = __ffsll(mk) - 1;
    unsigned aboveS = __shfl(above, src, 64);
    int j = lane & 31;
    unsigned cj = hist[(src << 5) + j];               // consecutive words: conflict-free
    unsigned P = cj;
    #pragma unroll
    for (int off = 1; off < 32; off <<= 1) {          // width-32 scan (both halves identical)
        unsigned n = __shfl_up(P, off, 32);
        if (j >= off) P += n;
    }
    unsigned T32 = __shfl(P, 31, 32);
    unsigned above_j = aboveS + T32 - P;              // keys strictly above bin src*32+j
    bool h2 = (above_j < rr_in) && (rr_in <= above_j + cj);
    unsigned long long mk2 = __ballot(h2);
    int src2 = __ffsll(mk2) - 1;
    bin = ((unsigned)src << 5) | (unsigned)(src2 & 31);
    rr  = rr_in - __shfl(above_j, src2, 64);
}

// find rank rr_in in 256-bin histogram (lane owns 4 bins via uint4)
__device__ __forceinline__ void select256(const unsigned* h, int lane,
                                          unsigned rr_in, unsigned& sub, unsigned& rr) {
    uint4 c = *reinterpret_cast<const uint4*>(&h[lane << 2]);
    unsigned T = c.x + c.y + c.z + c.w;
    unsigned incl, tot; wscan(T, lane, incl, tot);
    unsigned above = tot - incl;
    bool hit = (above < rr_in) && (rr_in <= above + T);
    unsigned long long mk = __ballot(hit);
    int src = __ffsll(mk) - 1;
    unsigned aS = __shfl(above, src, 64);
    unsigned c0 = __shfl(c.x, src, 64), c1 = __shfl(c.y, src, 64);
    unsigned c2 = __shfl(c.z, src, 64), c3 = __shfl(c.w, src, 64);
    unsigned a3 = aS, a2 = a3 + c3, a1 = a2 + c2, a0 = a1 + c1;
    unsigned b, a;
    if      (a3 < rr_in && rr_in <= a3 + c3) { b = 3u; a = a3; }
    else if (a2 < rr_in && rr_in <= a2 + c2) { b = 2u; a = a2; }
    else if (a1 < rr_in && rr_in <= a1 + c1) { b = 1u; a = a1; }
    else                                     { b = 0u; a = a0; }
    sub = ((unsigned)src << 2) | b;
    rr  = rr_in - a;
}

// ------------- kernel 3: block-per-row, candidate-compaction dual select -------------
__global__ __launch_bounds__(NT)
void k_select_apply(const float4* __restrict__ x4, const float4* __restrict__ factor4,
                    const float4* __restrict__ mean4, float4* __restrict__ out4,
                    int rankHi, int rankLo) {
    __shared__ __align__(16) unsigned hist1[NBIN1];
    __shared__ __align__(16) unsigned h8[2][256];
    __shared__ unsigned candK[CAP1];
    __shared__ unsigned candS[CAP0];
    __shared__ unsigned fin[2][CAPF];
    __shared__ unsigned cnts[4];     // [0]=cand kth, [1]=cand top, [2]=fin kth, [3]=fin top
    __shared__ unsigned res[2];      // [0]=keyHi(rank7), [1]=keyLo(rank211)

    const int t    = threadIdx.x;
    const int wid  = t >> 6;
    const int lane = t & 63;
    const size_t rowBase = (size_t)blockIdx.x * FEAT4;

    // ---- zero ----
    #pragma unroll
    for (int i = 0; i < NBIN1 / NT; ++i) hist1[t + NT * i] = 0u;
    h8[0][t] = 0u; h8[1][t] = 0u;
    if (t < 4) cnts[t] = 0u;
    __syncthreads();                                   // B1

    // ---- phase A: keygen (keys stay in VGPRs) + 11-bit histogram ----
    unsigned kk[16];
    #pragma unroll
    for (int jj = 0; jj < 4; ++jj) {
        int v = t + NT * jj;
        float4 X  = x4[rowBase + v];
        float4 Fa = factor4[v];
        unsigned k0 = fkey(X.x * Fa.x), k1 = fkey(X.y * Fa.y);
        unsigned k2 = fkey(X.z * Fa.z), k3 = fkey(X.w * Fa.w);
        kk[4*jj+0] = k0; kk[4*jj+1] = k1; kk[4*jj+2] = k2; kk[4*jj+3] = k3;
        atomicAdd(&hist1[k0 >> 21], 1u);
        atomicAdd(&hist1[k1 >> 21], 1u);
        atomicAdd(&hist1[k2 >> 21], 1u);
        atomicAdd(&hist1[k3 >> 21], 1u);
    }
    __syncthreads();                                   // B2

    // ---- phase B: one scan of 2048 bins resolves BOTH ranks (redundant per wave) ----
    unsigned bin0, rr0, bin1, rr1;
    {
        unsigned T = 0;
        #pragma unroll
        for (int j = 0; j < 32; ++j)                   // bank-rotated: conflict-free
            T += hist1[(lane << 5) + ((j + lane) & 31)];
        unsigned incl, tot; wscan(T, lane, incl, tot);
        unsigned above = tot - incl;
        resolve2048(hist1, lane, T, above, (unsigned)rankHi, bin0, rr0);
        resolve2048(hist1, lane, T, above, (unsigned)rankLo, bin1, rr1);
    }

    // ---- phase C: compact candidates + fused 8-bit sub-histograms ----
    #pragma unroll
    for (int j = 0; j < 16; ++j) {
        unsigned k = kk[j];
        unsigned d = k >> 21;
        if (d == bin1) {
            unsigned idx = atomicAdd(&cnts[0], 1u);
            if (idx < CAP1) { candK[idx] = k; atomicAdd(&h8[1][(k >> 13) & 255u], 1u); }
        }
        if (d == bin0) {
            unsigned idx = atomicAdd(&cnts[1], 1u);
            if (idx < CAP0) { candS[idx] = k; atomicAdd(&h8[0][(k >> 13) & 255u], 1u); }
        }
    }
    __syncthreads();                                   // B3

    // ---- phase D: resolve 8-bit sub-digit within each candidate pool ----
    unsigned sub0, rr0f, sub1, rr1f;
    select256(&h8[0][0], lane, rr0, sub0, rr0f);
    select256(&h8[1][0], lane, rr1, sub1, rr1f);

    // ---- phase E: gather finalists (19-bit prefix match) ----
    {
        unsigned pre1 = (bin1 << 8) | sub1;
        unsigned pre0 = (bin0 << 8) | sub0;
        unsigned K1c = cnts[0]; if (K1c > CAP1) K1c = CAP1;
        for (unsigned i = t; i < K1c; i += NT) {
            unsigned k = candK[i];
            if ((k >> 13) == pre1) { unsigned f = atomicAdd(&cnts[2], 1u); if (f < CAPF) fin[1][f] = k; }
        }
        unsigned K0c = cnts[1]; if (K0c > CAP0) K0c = CAP0;
        for (unsigned i = t; i < K0c; i += NT) {
            unsigned k = candS[i];
            if ((k >> 13) == pre0) { unsigned f = atomicAdd(&cnts[3], 1u); if (f < CAPF) fin[0][f] = k; }
        }
    }
    __syncthreads();                                   // B4

    // ---- phase F: exact rank by duplicate-aware counting (waves 0,1 in parallel) ----
    if (wid < 2) {
        unsigned K  = cnts[wid == 0 ? 3 : 2]; if (K > CAPF) K = CAPF;
        unsigned rr = (wid == 0) ? rr0f : rr1f;
        unsigned myk = fin[wid][lane < (int)K ? lane : 0];
        unsigned gt = 0, eq = 0;
        for (unsigned i = 0; i < K; ++i) {
            unsigned v = fin[wid][i];                  // broadcast read
            gt += (v > myk) ? 1u : 0u;
            eq += (v == myk) ? 1u : 0u;
        }
        bool hit = (lane < (int)K) && (gt < rr) && (rr <= gt + eq);
        unsigned long long mk = __ballot(hit);
        int src = __ffsll(mk) - 1;
        unsigned key = __shfl(myk, src, 64);
        if (lane == 0) res[wid] = key;
    }
    __syncthreads();                                   // B5

    // ---- phase G: apply masks (x re-read: L1/L2-hot) ----
    const unsigned keyHi = res[0];
    const unsigned keyLo = res[1];
    #pragma unroll
    for (int jj = 0; jj < 4; ++jj) {
        int v = t + NT * jj;
        float4 X = x4[rowBase + v];
        float4 M = mean4[v];
        unsigned k0 = kk[4*jj+0], k1 = kk[4*jj+1], k2 = kk[4*jj+2], k3 = kk[4*jj+3];
        vfloat4 o;
        o.x = (k0 <= keyHi) ? ((k0 >= keyLo) ? X.x - M.x : -M.x) : 0.0f;
        o.y = (k1 <= keyHi) ? ((k1 >= keyLo) ? X.y - M.y : -M.y) : 0.0f;
        o.z = (k2 <= keyHi) ? ((k2 >= keyLo) ? X.z - M.z : -M.z) : 0.0f;
        o.w = (k3 <= keyHi) ? ((k3 >= keyLo) ? X.w - M.w : -M.w) : 0.0f;
        __builtin_nontemporal_store(o, reinterpret_cast<vfloat4*>(&out4[rowBase + v]));
    }
}

extern "C" void kernel_launch(void* const* d_in, const int* in_sizes, int n_in,
                              void* d_out, int out_size, void* d_ws, size_t ws_size,
                              hipStream_t stream) {
    const float* x  = (const float*)d_in[0];
    const float* aa = (const float*)d_in[1];
    float* out = (float*)d_out;

    const int F   = in_sizes[1];          // 4096
    const int B   = in_sizes[0] / F;      // 8192
    const int F4v = F / 4;
    const int rankLo = (int)((double)F * 0.05) + TOP_IG;   // 211
    const int rankHi = TOP_IG;                              // 7

    int nChunks = 256;
    while (nChunks > 1 &&
           ((size_t)nChunks + 2) * (size_t)F * sizeof(float) > ws_size)
        nChunks >>= 1;
    if (nChunks > B) nChunks = B;

    float* part   = (float*)d_ws;
    float* mean   = part + (size_t)nChunks * F;
    float* factor = mean + F;
    int rpc = (B + nChunks - 1) / nChunks;

    dim3 g1((F4v + NT1 - 1) / NT1, nChunks);
    k_colsum_partial<<<g1, NT1, 0, stream>>>((const float4*)x, (float4*)part, B, F4v, rpc);

    k_finalize_stats<<<dim3((F4v + 63) / 64), NT, 0, stream>>>(
        (const float4*)part, (const float4*)aa, (float4*)mean, (float4*)factor, B, F4v, nChunks);

    k_select_apply<<<dim3(B), NT, 0, stream>>>(
        (const float4*)x, (const float4*)factor, (const float4*)mean, (float4*)out,
        rankHi, rankLo);
}

// Round 8
// 111.511 us; speedup vs baseline: 2.1083x; 1.0138x over previous
//
#include <hip/hip_runtime.h>
#include <cstdint>
#include <cmath>

#define DENSITY   0.05f
#define TOP_IG    7
#define NT        256
#define NT1       64
#define FEAT      4096
#define FEAT4     1024
#define NBIN1     2048     // 11-bit pass-1 digit
#define CAP1      1024     // candidate cap, kth target (typ ~220)
#define CAP0      512      // candidate cap, top_ig target (typ ~10)
#define CAPF      64       // finalist cap (typ ~2)

typedef float vfloat4 __attribute__((ext_vector_type(4)));

// monotonic float -> uint order key (ascending float == ascending key)
__device__ __forceinline__ unsigned fkey(float f) {
    unsigned u = __float_as_uint(f);
    return (u & 0x80000000u) ? ~u : (u | 0x80000000u);
}

// ---------------- kernel 1: chunked column partial sums (R3 geometry, frozen) ----------------
__global__ __launch_bounds__(NT1)
void k_colsum_partial(const float4* __restrict__ x4, float4* __restrict__ part4,
                      int B, int F4v, int rowsPerChunk) {
    int cg = blockIdx.x * NT1 + threadIdx.x;
    if (cg >= F4v) return;
    int r0 = blockIdx.y * rowsPerChunk;
    int r1 = r0 + rowsPerChunk; if (r1 > B) r1 = B;
    float4 s0 = make_float4(0.f,0.f,0.f,0.f), s1 = s0, s2 = s0, s3 = s0;
    int r = r0;
    for (; r + 4 <= r1; r += 4) {
        float4 a = x4[(size_t)(r+0) * F4v + cg];
        float4 b = x4[(size_t)(r+1) * F4v + cg];
        float4 c = x4[(size_t)(r+2) * F4v + cg];
        float4 d = x4[(size_t)(r+3) * F4v + cg];
        s0.x += a.x; s0.y += a.y; s0.z += a.z; s0.w += a.w;
        s1.x += b.x; s1.y += b.y; s1.z += b.z; s1.w += b.w;
        s2.x += c.x; s2.y += c.y; s2.z += c.z; s2.w += c.w;
        s3.x += d.x; s3.y += d.y; s3.z += d.z; s3.w += d.w;
    }
    for (; r < r1; ++r) {
        float4 a = x4[(size_t)r * F4v + cg];
        s0.x += a.x; s0.y += a.y; s0.z += a.z; s0.w += a.w;
    }
    float4 s = make_float4(s0.x+s1.x+s2.x+s3.x, s0.y+s1.y+s2.y+s3.y,
                           s0.z+s1.z+s2.z+s3.z, s0.w+s1.w+s2.w+s3.w);
    part4[(size_t)blockIdx.y * F4v + cg] = s;
}

// ------------- kernel 2: reduce partials -> mean; compute factor (frozen) -------------
__global__ __launch_bounds__(NT)
void k_finalize_stats(const float4* __restrict__ part4, const float4* __restrict__ aa4,
                      float4* __restrict__ mean4, float4* __restrict__ factor4,
                      int B, int F4v, int nChunks) {
    __shared__ float4 red[4][64];
    int lane = threadIdx.x & 63;
    int q    = threadIdx.x >> 6;
    int cg   = blockIdx.x * 64 + lane;
    float4 s = make_float4(0.f, 0.f, 0.f, 0.f);
    if (cg < F4v) {
        for (int ch = q; ch < nChunks; ch += 4) {
            float4 v = part4[(size_t)ch * F4v + cg];
            s.x += v.x; s.y += v.y; s.z += v.z; s.w += v.w;
        }
    }
    red[q][lane] = s;
    __syncthreads();
    if (q == 0 && cg < F4v) {
        float4 a0 = red[0][lane], a1 = red[1][lane], a2 = red[2][lane], a3 = red[3][lane];
        float invB = 1.0f / (float)B;
        mean4[cg] = make_float4((a0.x + a1.x + a2.x + a3.x) * invB,
                                (a0.y + a1.y + a2.y + a3.y) * invB,
                                (a0.z + a1.z + a2.z + a3.z) * invB,
                                (a0.w + a1.w + a2.w + a3.w) * invB);
        float4 a = aa4[cg];
        factor4[cg] = make_float4((float)exp((double)(DENSITY - a.x)),
                                  (float)exp((double)(DENSITY - a.y)),
                                  (float)exp((double)(DENSITY - a.z)),
                                  (float)exp((double)(DENSITY - a.w)));
    }
}

// wave inclusive scan + total of per-lane value
__device__ __forceinline__ void wscan(unsigned T, int lane, unsigned& incl, unsigned& tot) {
    unsigned P = T;
    #pragma unroll
    for (int off = 1; off < 64; off <<= 1) {
        unsigned n = __shfl_up(P, off, 64);
        if (lane >= off) P += n;
    }
    incl = P;
    tot = __shfl(P, 63, 64);
}

// find rank rr_in in 256-bin histogram (lane owns 4 bins via uint4)
__device__ __forceinline__ void select256(const unsigned* h, int lane,
                                          unsigned rr_in, unsigned& sub, unsigned& rr) {
    uint4 c = *reinterpret_cast<const uint4*>(&h[lane << 2]);
    unsigned T = c.x + c.y + c.z + c.w;
    unsigned incl, tot; wscan(T, lane, incl, tot);
    unsigned above = tot - incl;
    bool hit = (above < rr_in) && (rr_in <= above + T);
    unsigned long long mk = __ballot(hit);
    int src = __ffsll(mk) - 1;
    unsigned aS = __shfl(above, src, 64);
    unsigned c0 = __shfl(c.x, src, 64), c1 = __shfl(c.y, src, 64);
    unsigned c2 = __shfl(c.z, src, 64), c3 = __shfl(c.w, src, 64);
    unsigned a3 = aS, a2 = a3 + c3, a1 = a2 + c2, a0 = a1 + c1;
    unsigned b, a;
    if      (a3 < rr_in && rr_in <= a3 + c3) { b = 3u; a = a3; }
    else if (a2 < rr_in && rr_in <= a2 + c2) { b = 2u; a = a2; }
    else if (a1 < rr_in && rr_in <= a1 + c1) { b = 1u; a = a1; }
    else                                     { b = 0u; a = a0; }
    sub = ((unsigned)src << 2) | b;
    rr  = rr_in - a;
}

// ------------- kernel 3: block-per-row, windowed dual select + compaction -------------
__global__ __launch_bounds__(NT)
void k_select_apply(const float4* __restrict__ x4, const float4* __restrict__ factor4,
                    const float4* __restrict__ mean4, float4* __restrict__ out4,
                    int rankHi, int rankLo) {
    __shared__ __align__(16) unsigned hist1[NBIN1];
    __shared__ __align__(16) unsigned h8[2][256];   // [0]=top_ig target, [1]=kth target
    __shared__ unsigned candS[CAP0];                // top_ig candidates
    __shared__ unsigned candK[CAP1];                // kth candidates
    __shared__ unsigned fin[2][CAPF];
    __shared__ unsigned cnts[4];    // [g]=cand count, [2+g]=finalist count (g: 0=S,1=K)
    __shared__ unsigned smax[4];    // per-wave max key
    __shared__ unsigned res[2];     // [0]=keyHi(rank7), [1]=keyLo(rank211)

    const int t    = threadIdx.x;
    const int wid  = t >> 6;
    const int lane = t & 63;
    const size_t rowBase = (size_t)blockIdx.x * FEAT4;

    // ---- zero ----
    #pragma unroll
    for (int i = 0; i < NBIN1 / NT; ++i) hist1[t + NT * i] = 0u;
    h8[0][t] = 0u; h8[1][t] = 0u;
    if (t < 4) cnts[t] = 0u;
    __syncthreads();                                   // B1

    // ---- phase A: keygen (keys stay in VGPRs) + 11-bit histogram + wave max ----
    unsigned kk[16];
    unsigned wm = 0u;
    #pragma unroll
    for (int jj = 0; jj < 4; ++jj) {
        int v = t + NT * jj;
        float4 X  = x4[rowBase + v];
        float4 Fa = factor4[v];
        unsigned k0 = fkey(X.x * Fa.x), k1 = fkey(X.y * Fa.y);
        unsigned k2 = fkey(X.z * Fa.z), k3 = fkey(X.w * Fa.w);
        kk[4*jj+0] = k0; kk[4*jj+1] = k1; kk[4*jj+2] = k2; kk[4*jj+3] = k3;
        wm = max(max(wm, max(k0, k1)), max(k2, k3));
        atomicAdd(&hist1[k0 >> 21], 1u);
        atomicAdd(&hist1[k1 >> 21], 1u);
        atomicAdd(&hist1[k2 >> 21], 1u);
        atomicAdd(&hist1[k3 >> 21], 1u);
    }
    #pragma unroll
    for (int off = 32; off > 0; off >>= 1)
        wm = max(wm, (unsigned)__shfl_xor(wm, off, 64));
    if (lane == 0) smax[wid] = wm;
    __syncthreads();                                   // B2

    // ---- phase B: windowed suffix scan from the top bin; resolves BOTH ranks ----
    unsigned bin0, rrem0 = (unsigned)rankHi;           // rank 7 (top_ig)
    unsigned bin1, rrem1 = (unsigned)rankLo;           // rank 211 (kth)
    {
        unsigned bm = max(max(smax[0], smax[1]), max(smax[2], smax[3]));
        int wstart = (int)(bm >> 21);                  // top nonempty bin
        bool f0 = false, f1 = false;
        unsigned base = 0u;
        while (!(f0 && f1)) {
            int b = wstart - lane;
            unsigned c = (b >= 0) ? hist1[b] : 0u;
            unsigned incl, tot; wscan(c, lane, incl, tot);
            unsigned above = base + incl - c;          // keys in bins strictly above b
            unsigned cum   = base + incl;
            if (!f0) {
                bool hit = (above < rrem0) && (rrem0 <= cum);
                unsigned long long mk = __ballot(hit);
                if (mk) { int s = __ffsll(mk) - 1; bin0 = (unsigned)(wstart - s);
                          rrem0 -= __shfl(above, s, 64); f0 = true; }
            }
            if (!f1) {
                bool hit = (above < rrem1) && (rrem1 <= cum);
                unsigned long long mk = __ballot(hit);
                if (mk) { int s = __ffsll(mk) - 1; bin1 = (unsigned)(wstart - s);
                          rrem1 -= __shfl(above, s, 64); f1 = true; }
            }
            base += tot;
            wstart -= 64;
        }
    }

    // ---- phase C: compact candidates + fused 8-bit sub-histograms ----
    #pragma unroll
    for (int j = 0; j < 16; ++j) {
        unsigned k = kk[j];
        unsigned d = k >> 21;
        if (d == bin1) {
            unsigned idx = atomicAdd(&cnts[1], 1u);
            if (idx < CAP1) { candK[idx] = k; atomicAdd(&h8[1][(k >> 13) & 255u], 1u); }
        }
        if (d == bin0) {
            unsigned idx = atomicAdd(&cnts[0], 1u);
            if (idx < CAP0) { candS[idx] = k; atomicAdd(&h8[0][(k >> 13) & 255u], 1u); }
        }
    }
    __syncthreads();                                   // B3

    // ---- phase D+E: TARGET-PARALLEL. waves 0-1: top_ig (g=0); waves 2-3: kth (g=1) ----
    const int g = wid >> 1;
    unsigned subX, rrXf;
    select256(&h8[g][0], lane, (g == 0) ? rrem0 : rrem1, subX, rrXf);
    {
        unsigned binX = (g == 0) ? bin0 : bin1;
        unsigned preX = (binX << 8) | subX;
        unsigned Kc = cnts[g]; unsigned cap = (g == 0) ? CAP0 : CAP1; if (Kc > cap) Kc = cap;
        const unsigned* cand = (g == 0) ? candS : candK;
        for (unsigned i = (unsigned)(t & 127); i < Kc; i += 128) {
            unsigned k = cand[i];
            if ((k >> 13) == preX) {
                unsigned f = atomicAdd(&cnts[2 + g], 1u);
                if (f < CAPF) fin[g][f] = k;
            }
        }
    }
    __syncthreads();                                   // B4

    // ---- phase F: exact rank by duplicate-aware counting (waves 0 and 2) ----
    if ((wid & 1) == 0) {
        unsigned K = cnts[2 + g]; if (K > CAPF) K = CAPF;
        unsigned myk = fin[g][lane < (int)K ? lane : 0];
        unsigned gt = 0, eq = 0;
        for (unsigned i = 0; i < K; ++i) {
            unsigned v = fin[g][i];                    // broadcast read
            gt += (v > myk) ? 1u : 0u;
            eq += (v == myk) ? 1u : 0u;
        }
        bool hit = (lane < (int)K) && (gt < rrXf) && (rrXf <= gt + eq);
        unsigned long long mk = __ballot(hit);
        int src = __ffsll(mk) - 1;
        unsigned key = __shfl(myk, src, 64);
        if (lane == 0) res[g] = key;
    }
    __syncthreads();                                   // B5

    // ---- phase G: apply masks (x re-read: L1/L2-hot) ----
    const unsigned keyHi = res[0];
    const unsigned keyLo = res[1];
    #pragma unroll
    for (int jj = 0; jj < 4; ++jj) {
        int v = t + NT * jj;
        float4 X = x4[rowBase + v];
        float4 M = mean4[v];
        unsigned k0 = kk[4*jj+0], k1 = kk[4*jj+1], k2 = kk[4*jj+2], k3 = kk[4*jj+3];
        vfloat4 o;
        o.x = (k0 <= keyHi) ? ((k0 >= keyLo) ? X.x - M.x : -M.x) : 0.0f;
        o.y = (k1 <= keyHi) ? ((k1 >= keyLo) ? X.y - M.y : -M.y) : 0.0f;
        o.z = (k2 <= keyHi) ? ((k2 >= keyLo) ? X.z - M.z : -M.z) : 0.0f;
        o.w = (k3 <= keyHi) ? ((k3 >= keyLo) ? X.w - M.w : -M.w) : 0.0f;
        __builtin_nontemporal_store(o, reinterpret_cast<vfloat4*>(&out4[rowBase + v]));
    }
}

extern "C" void kernel_launch(void* const* d_in, const int* in_sizes, int n_in,
                              void* d_out, int out_size, void* d_ws, size_t ws_size,
                              hipStream_t stream) {
    const float* x  = (const float*)d_in[0];
    const float* aa = (const float*)d_in[1];
    float* out = (float*)d_out;

    const int F   = in_sizes[1];          // 4096
    const int B   = in_sizes[0] / F;      // 8192
    const int F4v = F / 4;
    const int rankLo = (int)((double)F * 0.05) + TOP_IG;   // 211
    const int rankHi = TOP_IG;                              // 7

    int nChunks = 256;
    while (nChunks > 1 &&
           ((size_t)nChunks + 2) * (size_t)F * sizeof(float) > ws_size)
        nChunks >>= 1;
    if (nChunks > B) nChunks = B;

    float* part   = (float*)d_ws;
    float* mean   = part + (size_t)nChunks * F;
    float* factor = mean + F;
    int rpc = (B + nChunks - 1) / nChunks;

    dim3 g1((F4v + NT1 - 1) / NT1, nChunks);
    k_colsum_partial<<<g1, NT1, 0, stream>>>((const float4*)x, (float4*)part, B, F4v, rpc);

    k_finalize_stats<<<dim3((F4v + 63) / 64), NT, 0, stream>>>(
        (const float4*)part, (const float4*)aa, (float4*)mean, (float4*)factor, B, F4v, nChunks);

    k_select_apply<<<dim3(B), NT, 0, stream>>>(
        (const float4*)x, (const float4*)factor, (const float4*)mean, (float4*)out,
        rankHi, rankLo);
}